// Round 2
// baseline (868.952 us; speedup 1.0000x reference)
//
#include <hip/hip_runtime.h>
#include <hip/hip_bf16.h>

#define ROWS 256
#define COLS 256
#define BATCH 16
#define FDIM 64
#define NPIX (ROWS * COLS)      // 65536
#define MTOT (BATCH * NPIX)     // 1048576

typedef __attribute__((ext_vector_type(8))) short short8;
typedef __attribute__((ext_vector_type(4))) float floatx4;

__device__ __forceinline__ unsigned short f2bf(float f) {
    union { float f; unsigned int i; } v;
    v.f = f;
    unsigned int r = v.i + 0x7FFFu + ((v.i >> 16) & 1u);  // RNE
    return (unsigned short)(r >> 16);
}
__device__ __forceinline__ float bf2f(unsigned short u) {
    union { unsigned int i; float f; } v;
    v.i = ((unsigned int)u) << 16;
    return v.f;
}
__device__ __forceinline__ short8 pack8(float4 x, float4 y) {
    short8 o;
    o[0] = (short)f2bf(x.x); o[1] = (short)f2bf(x.y);
    o[2] = (short)f2bf(x.z); o[3] = (short)f2bf(x.w);
    o[4] = (short)f2bf(y.x); o[5] = (short)f2bf(y.y);
    o[6] = (short)f2bf(y.z); o[7] = (short)f2bf(y.w);
    return o;
}
__device__ __forceinline__ float dinv(int r, int c) {
    int rv = 3 - (r == 0) - (r == ROWS - 1);
    int cv = 3 - (c == 0) - (c == COLS - 1);
    return rsqrtf((float)(rv * cv) + 1e-5f);
}

// ---------------------------------------------------------------------------
// K1: per-feature sum / sumsq of Ht = H @ W (bf16 MFMA, fp32 acc, fp32 inputs).
// Ht is NOT stored (recomputed in K3) -> no large workspace needed.
// A layout: A[m=lane&15][k=quad*8+j]; B layout: B[k=quad*8+j][n=lane&15];
// C/D: col=lane&15, row=quad*4+reg
// ---------------------------------------------------------------------------
__global__ __launch_bounds__(256) void k1_stats(
    const float* __restrict__ H,    // [MTOT,64] fp32
    const float* __restrict__ W,    // [64,64]  fp32 row-major [in][out]
    float* __restrict__ stats)      // [128] fp32: sum[64], sumsq[64]
{
    const int lane = threadIdx.x & 63;
    const int wid  = threadIdx.x >> 6;
    const int gw   = blockIdx.x * 4 + wid;
    const int nw   = gridDim.x * 4;
    const int n    = lane & 15;
    const int q    = lane >> 4;

    short8 bfrag[2][4];
    for (int kt = 0; kt < 2; ++kt)
        for (int nt = 0; nt < 4; ++nt)
            for (int j = 0; j < 8; ++j)
                bfrag[kt][nt][j] = (short)f2bf(W[(kt * 32 + q * 8 + j) * FDIM + nt * 16 + n]);

    float s[4]  = {0.f, 0.f, 0.f, 0.f};
    float s2[4] = {0.f, 0.f, 0.f, 0.f};

    const int ntiles = MTOT / 16;
    for (int t = gw; t < ntiles; t += nw) {
        const float4* ap = (const float4*)(H + ((size_t)t * 16 + n) * FDIM + q * 8);
        short8 a0 = pack8(ap[0], ap[1]);   // k = q*8 .. q*8+7
        short8 a1 = pack8(ap[8], ap[9]);   // k = 32 + q*8 ..

        floatx4 acc[4] = {};
        for (int nt = 0; nt < 4; ++nt) {
            acc[nt] = __builtin_amdgcn_mfma_f32_16x16x32_bf16(a0, bfrag[0][nt], acc[nt], 0, 0, 0);
            acc[nt] = __builtin_amdgcn_mfma_f32_16x16x32_bf16(a1, bfrag[1][nt], acc[nt], 0, 0, 0);
        }
        for (int nt = 0; nt < 4; ++nt)
            for (int r = 0; r < 4; ++r) {
                float v = acc[nt][r];
                s[nt] += v;
                s2[nt] = fmaf(v, v, s2[nt]);
            }
    }

    for (int nt = 0; nt < 4; ++nt) {
        float a = s[nt], b = s2[nt];
        a += __shfl_xor(a, 16); b += __shfl_xor(b, 16);
        a += __shfl_xor(a, 32); b += __shfl_xor(b, 32);
        if (q == 0) {
            atomicAdd(&stats[nt * 16 + n], a);
            atomicAdd(&stats[64 + nt * 16 + n], b);
        }
    }
}

// ---------------------------------------------------------------------------
// K2: fold BN into per-feature affine: a = gamma*rsqrt(var+eps), b = beta-mean*a
// ---------------------------------------------------------------------------
__global__ void k2_finalize(const float* __restrict__ stats,
                            const float* __restrict__ gamma,
                            const float* __restrict__ beta,
                            float* __restrict__ ab)
{
    int t = threadIdx.x;
    if (t < 64) {
        const float inv_m = 1.0f / (float)MTOT;
        float mean = stats[t] * inv_m;
        float var  = stats[64 + t] * inv_m - mean * mean;
        float a = gamma[t] * rsqrtf(var + 1e-5f);
        ab[t]      = a;
        ab[64 + t] = beta[t] - mean * a;
    }
}

// ---------------------------------------------------------------------------
// K3: per (batch, 8x32 output tile): recompute Ht = H@W for the 10x34 halo
// via MFMA, apply affine+relu+*d_j into LDS (bf16), then 9-point stencil,
// *d_i, write fp32 out.
// ---------------------------------------------------------------------------
#define TH 8
#define TW 32
#define IH (TH + 2)
#define IW (TW + 2)
#define NHALO (IH * IW)        // 340
#define NCHUNK 22              // ceil(340/16)

__global__ __launch_bounds__(256) void k3_fused(
    const float* __restrict__ H,
    const float* __restrict__ W,
    const float* __restrict__ ab,
    float* __restrict__ out)
{
    __shared__ unsigned short P[NHALO * FDIM];   // 43,520 B
    __shared__ float abv[2 * FDIM];

    const int tid  = threadIdx.x;
    const int lane = tid & 63;
    const int wid  = tid >> 6;
    const int n    = lane & 15;
    const int q    = lane >> 4;

    int bid = blockIdx.x;
    const int ct = bid & 7;   bid >>= 3;   // 8 col tiles
    const int rt = bid & 31;  bid >>= 5;   // 32 row tiles
    const int bb = bid;                    // batch
    const int r0 = rt * TH, c0 = ct * TW;
    const size_t base = (size_t)bb * NPIX * FDIM;

    if (tid < 128) abv[tid] = ab[tid];

    short8 bfrag[2][4];
    for (int kt = 0; kt < 2; ++kt)
        for (int nt = 0; nt < 4; ++nt)
            for (int j = 0; j < 8; ++j)
                bfrag[kt][nt][j] = (short)f2bf(W[(kt * 32 + q * 8 + j) * FDIM + nt * 16 + n]);
    __syncthreads();

    // Phase A: GEMM -> affine -> relu -> *d_j -> LDS (bf16)
    for (int ch = wid; ch < NCHUNK; ch += 4) {
        int p = ch * 16 + n;
        short8 a0 = {}; short8 a1 = {};
        if (p < NHALO) {
            int ri = p / IW, ci = p - ri * IW;
            int r = r0 - 1 + ri, c = c0 - 1 + ci;
            if ((unsigned)r < ROWS && (unsigned)c < COLS) {
                const float4* apx = (const float4*)(H + base + (size_t)(r * COLS + c) * FDIM + q * 8);
                a0 = pack8(apx[0], apx[1]);
                a1 = pack8(apx[8], apx[9]);
            }
        }
        floatx4 acc[4] = {};
        for (int nt = 0; nt < 4; ++nt) {
            acc[nt] = __builtin_amdgcn_mfma_f32_16x16x32_bf16(a0, bfrag[0][nt], acc[nt], 0, 0, 0);
            acc[nt] = __builtin_amdgcn_mfma_f32_16x16x32_bf16(a1, bfrag[1][nt], acc[nt], 0, 0, 0);
        }
        for (int nt = 0; nt < 4; ++nt) {
            float av = abv[nt * 16 + n], bv = abv[64 + nt * 16 + n];
            for (int rr = 0; rr < 4; ++rr) {
                int pp = ch * 16 + q * 4 + rr;
                if (pp < NHALO) {
                    int ri = pp / IW, ci = pp - ri * IW;
                    int r = r0 - 1 + ri, c = c0 - 1 + ci;
                    float d = 0.f;
                    if ((unsigned)r < ROWS && (unsigned)c < COLS) d = dinv(r, c);
                    float y = fmaxf(fmaf(acc[nt][rr], av, bv), 0.f) * d;
                    P[pp * FDIM + nt * 16 + n] = f2bf(y);
                }
            }
        }
    }
    __syncthreads();

    // Phase B: 9-point stencil from LDS, * d_i, fp32 store
    const int fg = tid & 7;
    for (int po = tid >> 3; po < TH * TW; po += 32) {
        int orr = po >> 5;      // / TW
        int oc  = po & 31;      // % TW
        float acc8[8] = {0.f, 0.f, 0.f, 0.f, 0.f, 0.f, 0.f, 0.f};
        for (int dr = 0; dr < 3; ++dr)
            for (int dc = 0; dc < 3; ++dc) {
                const short8 v = *(const short8*)&P[((orr + dr) * IW + (oc + dc)) * FDIM + fg * 8];
                for (int j = 0; j < 8; ++j)
                    acc8[j] += bf2f((unsigned short)v[j]);
            }
        int r = r0 + orr, c = c0 + oc;
        float d = dinv(r, c);
        float4 o0, o1;
        o0.x = acc8[0] * d; o0.y = acc8[1] * d; o0.z = acc8[2] * d; o0.w = acc8[3] * d;
        o1.x = acc8[4] * d; o1.y = acc8[5] * d; o1.z = acc8[6] * d; o1.w = acc8[7] * d;
        float4* op = (float4*)(out + base + (size_t)(r * COLS + c) * FDIM + fg * 8);
        op[0] = o0; op[1] = o1;
    }
}

extern "C" void kernel_launch(void* const* d_in, const int* in_sizes, int n_in,
                              void* d_out, int out_size, void* d_ws, size_t ws_size,
                              hipStream_t stream) {
    const float* H     = (const float*)d_in[0];
    const float* W     = (const float*)d_in[1];
    const float* gamma = (const float*)d_in[2];
    const float* beta  = (const float*)d_in[3];
    float* out = (float*)d_out;

    float* stats = (float*)d_ws;        // [128]
    float* ab    = stats + 128;         // [128]

    hipMemsetAsync(stats, 0, 128 * sizeof(float), stream);
    k1_stats<<<4096, 256, 0, stream>>>(H, W, stats);
    k2_finalize<<<1, 64, 0, stream>>>(stats, gamma, beta, ab);
    k3_fused<<<BATCH * 32 * 8, 256, 0, stream>>>(H, W, ab, out);
}